// Round 8
// baseline (157.405 us; speedup 1.0000x reference)
//
#include <hip/hip_runtime.h>

#define BS 32
#define NA 512
#define ID 128
#define NH 8
#define HD 64
#define NHD 512   // NH*HD
#define NEG 0.2f
#define NC 32
#define CH 16

// K1: h_prime = h @ W (fp32). Block = 16 rows x 512 cols, 4 waves: wave w has
// rows (w>>1)*8..+7 (wave-uniform -> A via s_load, zero LDS) and cols
// (w&1)*256 + 4*lane (dense 1KB W loads). Proven R7.
__global__ __launch_bounds__(256) void k1_gemm(
    const float* __restrict__ h, const float* __restrict__ W,
    const float* __restrict__ att, float* __restrict__ hp,
    float* __restrict__ s_out, float* __restrict__ t_out) {
  int blk = blockIdx.x;
  int b = blk >> 5;
  int n0 = (blk & 31) * 16;
  int t = threadIdx.x;
  int lane = t & 63, w = t >> 6;
  int r0 = __builtin_amdgcn_readfirstlane((w >> 1) * 8);   // 0 or 8
  int chalf = __builtin_amdgcn_readfirstlane(w & 1);
  int col = chalf * 256 + lane * 4;
  int head = col >> 6;
  int d0 = col & 63;
  const float* arow = h + ((size_t)b * NA + n0 + r0) * ID;  // uniform base
  const float* wptr = W + col;

  float4 a0c = {0,0,0,0}, a1c = {0,0,0,0}, a2c = {0,0,0,0}, a3c = {0,0,0,0};
  float4 a4c = {0,0,0,0}, a5c = {0,0,0,0}, a6c = {0,0,0,0}, a7c = {0,0,0,0};

#define K1_ROW(I, C, KK)                                                      \
  { float a_ = arow[(I) * ID + kc + (KK)];                                    \
    C.x += a_ * wv.x; C.y += a_ * wv.y; C.z += a_ * wv.z; C.w += a_ * wv.w; }
  #pragma unroll 1
  for (int kc = 0; kc < ID; kc += 8) {
    #pragma unroll
    for (int kk = 0; kk < 8; ++kk) {
      float4 wv = *(const float4*)(wptr + (size_t)(kc + kk) * NHD);
      K1_ROW(0, a0c, kk) K1_ROW(1, a1c, kk) K1_ROW(2, a2c, kk)
      K1_ROW(3, a3c, kk) K1_ROW(4, a4c, kk) K1_ROW(5, a5c, kk)
      K1_ROW(6, a6c, kk) K1_ROW(7, a7c, kk)
    }
  }
#undef K1_ROW
  {
    size_t off = ((((size_t)b * NH + head) * NA) + (n0 + r0)) * HD + d0;
    *(float4*)(hp + off) = a0c; off += HD;
    *(float4*)(hp + off) = a1c; off += HD;
    *(float4*)(hp + off) = a2c; off += HD;
    *(float4*)(hp + off) = a3c; off += HD;
    *(float4*)(hp + off) = a4c; off += HD;
    *(float4*)(hp + off) = a5c; off += HD;
    *(float4*)(hp + off) = a6c; off += HD;
    *(float4*)(hp + off) = a7c;
  }
  {
    float4 as4 = *(const float4*)(att + head * 128 + d0);
    float4 ad4 = *(const float4*)(att + head * 128 + 64 + d0);
#define DOT4(C, A) ((C).x*(A).x + (C).y*(A).y + (C).z*(A).z + (C).w*(A).w)
    float sp0 = DOT4(a0c, as4), tp0 = DOT4(a0c, ad4);
    float sp1 = DOT4(a1c, as4), tp1 = DOT4(a1c, ad4);
    float sp2 = DOT4(a2c, as4), tp2 = DOT4(a2c, ad4);
    float sp3 = DOT4(a3c, as4), tp3 = DOT4(a3c, ad4);
    float sp4 = DOT4(a4c, as4), tp4 = DOT4(a4c, ad4);
    float sp5 = DOT4(a5c, as4), tp5 = DOT4(a5c, ad4);
    float sp6 = DOT4(a6c, as4), tp6 = DOT4(a6c, ad4);
    float sp7 = DOT4(a7c, as4), tp7 = DOT4(a7c, ad4);
#undef DOT4
    #pragma unroll
    for (int m = 1; m < 16; m <<= 1) {
      sp0 += __shfl_xor(sp0, m, 64); tp0 += __shfl_xor(tp0, m, 64);
      sp1 += __shfl_xor(sp1, m, 64); tp1 += __shfl_xor(tp1, m, 64);
      sp2 += __shfl_xor(sp2, m, 64); tp2 += __shfl_xor(tp2, m, 64);
      sp3 += __shfl_xor(sp3, m, 64); tp3 += __shfl_xor(tp3, m, 64);
      sp4 += __shfl_xor(sp4, m, 64); tp4 += __shfl_xor(tp4, m, 64);
      sp5 += __shfl_xor(sp5, m, 64); tp5 += __shfl_xor(tp5, m, 64);
      sp6 += __shfl_xor(sp6, m, 64); tp6 += __shfl_xor(tp6, m, 64);
      sp7 += __shfl_xor(sp7, m, 64); tp7 += __shfl_xor(tp7, m, 64);
    }
    int g16 = lane & 15;
    int rsel = g16 & 7;
    float sv_ = rsel == 0 ? sp0 : rsel == 1 ? sp1 : rsel == 2 ? sp2 :
                rsel == 3 ? sp3 : rsel == 4 ? sp4 : rsel == 5 ? sp5 :
                rsel == 6 ? sp6 : sp7;
    float tv_ = rsel == 0 ? tp0 : rsel == 1 ? tp1 : rsel == 2 ? tp2 :
                rsel == 3 ? tp3 : rsel == 4 ? tp4 : rsel == 5 ? tp5 :
                rsel == 6 ? tp6 : tp7;
    size_t off = (((size_t)b * NH + head) * NA) + n0 + r0 + rsel;
    if (g16 < 8) s_out[off] = sv_;
    else         t_out[off] = tv_;
  }
}

// K2 fused: per-(b,h) single kernel, no global tables.
// - double hybrid bitonic sort: t ascending, s DESCENDING (so js is monotone
//   non-decreasing over s-rank -> inline emission)
// - forward-only vector streams: sufP[js] = totP - preP[js] (scalar den uses
//   exact suffix zps, so only the numerator uses the subtraction; error
//   bounded ~eps * zps[0]/zps[js] * |v| << threshold)
// - wave w streams sorted rows [w*64,(w+1)*64), emitting each output row the
//   moment j reaches its js. One kernel, out is the only write.
__global__ __launch_bounds__(512) void k2_fused(
    const float* __restrict__ hp, const float* __restrict__ s_g,
    const float* __restrict__ t_g, float* __restrict__ out) {
  __shared__ float tv[NA]; __shared__ int tpm[NA];
  __shared__ float sv[NA]; __shared__ int spm[NA];
  __shared__ float wp[NA]; __shared__ float wn[NA];
  __shared__ float localP[8 * 64]; __shared__ float localN[8 * 64];
  __shared__ float seedP[8 * 64];  __shared__ float seedN[8 * 64];
  __shared__ float totP[64];
  __shared__ float zps[NA + 1]; __shared__ float znp[NA + 1];
  __shared__ float szP[NC]; __shared__ float szN[NC];
  __shared__ float sufZ[NC + 1]; __shared__ float preZ[NC + 1];
  __shared__ float aA[NA]; __shared__ float aB[NA]; __shared__ float aI[NA];
  __shared__ int aJ[NA]; __shared__ int aR[NA];

  int bh = blockIdx.x;
  int t = threadIdx.x;
  int lane = t & 63, w = t >> 6;
  const float* vbase = hp + (size_t)bh * NA * HD;

  // double hybrid bitonic sort (regs + shfl for stride<64, LDS for >=64)
  float tvr = t_g[(size_t)bh * NA + t]; int tir = t;
  float svr = s_g[(size_t)bh * NA + t]; int sir = t;
  for (int size = 2; size <= NA; size <<= 1) {
    bool dirAsc = ((t & size) == 0);
    for (int stride = size >> 1; stride > 0; stride >>= 1) {
      float ptv, psv; int pti, psi;
      if (stride >= 64) {
        tv[t] = tvr; tpm[t] = tir; sv[t] = svr; spm[t] = sir;
        __syncthreads();
        ptv = tv[t ^ stride]; pti = tpm[t ^ stride];
        psv = sv[t ^ stride]; psi = spm[t ^ stride];
        __syncthreads();
      } else {
        ptv = __shfl_xor(tvr, stride, 64); pti = __shfl_xor(tir, stride, 64);
        psv = __shfl_xor(svr, stride, 64); psi = __shfl_xor(sir, stride, 64);
      }
      bool mn = (((t & stride) == 0) == dirAsc);
      bool swt = mn ? (ptv < tvr) : (ptv > tvr);   // t ascending
      if (swt) { tvr = ptv; tir = pti; }
      bool sws = mn ? (psv > svr) : (psv < svr);   // s descending
      if (sws) { svr = psv; sir = psi; }
    }
  }
  tv[t] = tvr; tpm[t] = tir; sv[t] = svr; spm[t] = sir;
  __syncthreads();

  float cmax = fmaxf(tv[NA - 1], 0.f);
  float amax = fmaxf(sv[0], 0.f);       // sv sorted descending
  wp[t] = __expf(tv[t] - cmax);
  wn[t] = __expf(NEG * tv[t] - cmax);
  __syncthreads();

  // scalar 16-chunk sums + per-wave local vector sums over own 64 rows
  if (t < 32) {
    float a = 0.f;
    for (int j = t * CH; j < t * CH + CH; ++j) a += wp[j];
    szP[t] = a;
  } else if (t < 64) {
    int c = t - 32; float a = 0.f;
    for (int j = c * CH; j < c * CH + CH; ++j) a += wn[j];
    szN[c] = a;
  }
  {
    float aP = 0.f, aN = 0.f;
    int jb = w * 64;
    for (int jj = 0; jj < 64; ++jj) {
      int j = jb + jj;
      float vv = vbase[(size_t)tpm[j] * HD + lane];
      aP += wp[j] * vv;
      aN += wn[j] * vv;
    }
    localP[w * 64 + lane] = aP;
    localN[w * 64 + lane] = aN;
  }
  __syncthreads();

  // scans: scalar chunk scans (t=0,1) + cross-wave vector scan (t in [64,128))
  if (t == 0) {
    float run = 0.f; sufZ[NC] = 0.f;
    for (int cc = NC - 1; cc >= 0; --cc) { run += szP[cc]; sufZ[cc] = run; }
  } else if (t == 1) {
    float run = 0.f;
    for (int cc = 0; cc <= NC; ++cc) { preZ[cc] = run; if (cc < NC) run += szN[cc]; }
  } else if (t >= 64 && t < 128) {
    int d = t - 64;
    float run = 0.f;
    for (int u = 0; u < 8; ++u) { seedP[u * 64 + d] = run; run += localP[u * 64 + d]; }
    totP[d] = run;
    float run2 = 0.f;
    for (int u = 0; u < 8; ++u) { seedN[u * 64 + d] = run2; run2 += localN[u * 64 + d]; }
  }
  __syncthreads();

  // exact full-res scalar tables: zps (suffix of wp), znp (prefix of wn)
  {
    int ch = t >> 4;
    float a = 0.f;
    for (int k = t; k < ch * CH + CH; ++k) a += wp[k];
    zps[t] = a + sufZ[ch + 1];
    float b2 = 0.f;
    for (int k = ch * CH; k < t; ++k) b2 += wn[k];
    znp[t] = preZ[ch] + b2;
    if (t == 0) { zps[NA] = 0.f; znp[NA] = preZ[NC]; }
  }
  __syncthreads();

  // per-s-rank row info (t = s-rank, descending s -> js monotone nondecr.)
  {
    float sval = sv[t];
    float A = __expf(sval - amax);
    float B = __expf(NEG * sval - amax);
    float key = -sval;
    int lo = 0, hi = NA;
    while (lo < hi) { int mid = (lo + hi) >> 1; if (tv[mid] < key) lo = mid + 1; else hi = mid; }
    float den = A * zps[lo] + B * znp[lo];
    aA[t] = A; aB[t] = B; aI[t] = 1.f / den; aJ[t] = lo; aR[t] = spm[t];
  }
  __syncthreads();

  // stream + inline emission. wave w: j in [w*64, (w+1)*64)
  {
    int jlo = w * 64, jhi = jlo + 64;
    int p;
    { int lo = 0, hi = NA;
      while (lo < hi) { int mid = (lo + hi) >> 1; if (aJ[mid] < jlo) lo = mid + 1; else hi = mid; }
      p = lo; }
    float prePr = seedP[w * 64 + lane];
    float preNr = seedN[w * 64 + lane];
    float totPd = totP[lane];
    for (int j = jlo; j < jhi; ++j) {
      while (p < NA && aJ[p] == j) {
        float A = aA[p], B = aB[p], inv = aI[p]; int row = aR[p];
        float x = (A * (totPd - prePr) + B * preNr) * inv;
        out[((size_t)bh * NA + row) * HD + lane] = x > 0.f ? x : __expf(x) - 1.f;
        ++p;
      }
      float vv = vbase[(size_t)tpm[j] * HD + lane];
      prePr += wp[j] * vv;
      preNr += wn[j] * vv;
    }
    if (w == 7) {
      while (p < NA) {   // js == 512 rows (all-negative scores)
        float A = aA[p], B = aB[p], inv = aI[p]; int row = aR[p];
        float x = (A * (totPd - prePr) + B * preNr) * inv;
        out[((size_t)bh * NA + row) * HD + lane] = x > 0.f ? x : __expf(x) - 1.f;
        ++p;
      }
    }
  }
}

extern "C" void kernel_launch(void* const* d_in, const int* in_sizes, int n_in,
                              void* d_out, int out_size, void* d_ws, size_t ws_size,
                              hipStream_t stream) {
  const float* h  = (const float*)d_in[0];
  const float* W  = (const float*)d_in[1];
  const float* att = (const float*)d_in[2];
  float* out = (float*)d_out;
  // ws: hp 33.5MB | s 0.5MB | t 0.5MB  (~34.6 MB total)
  float* hp    = (float*)d_ws;
  float* s_arr = hp + (size_t)BS * NH * NA * HD;
  float* t_arr = s_arr + (size_t)BS * NH * NA;

  k1_gemm <<<dim3(1024), dim3(256), 0, stream>>>(h, W, att, hp, s_arr, t_arr);
  k2_fused<<<dim3(256),  dim3(512), 0, stream>>>(hp, s_arr, t_arr, out);
}